// Round 1
// 2322.297 us; speedup vs baseline: 1.0708x; 1.0708x over previous
//
#include <hip/hip_runtime.h>
#include <cstdint>
#include <cstddef>

typedef __bf16 bf16x8 __attribute__((ext_vector_type(8)));
typedef float  f32x4  __attribute__((ext_vector_type(4)));

typedef __attribute__((address_space(1))) void v_as1;
typedef __attribute__((address_space(3))) void v_as3;

#define NTOK 100352      // 2*224*224
#define DIMC 768
#define NHEAD 12
#define IMG 224
#define WN 7
#define WL 49

__device__ __forceinline__ unsigned short f2bf(float f) {
    uint32_t u = __float_as_uint(f);
    uint32_t r = (u + 0x7FFFu + ((u >> 16) & 1u)) >> 16;
    return (unsigned short)r;
}
__device__ __forceinline__ float bf2f(unsigned short u) {
    return __uint_as_float(((uint32_t)u) << 16);
}

__device__ __forceinline__ void async_cp16(const void* g, void* l) {
    __builtin_amdgcn_global_load_lds((v_as1*)g, (v_as3*)l, 16, 0, 0);
}

// ---------------- hi/lo bf16 split ----------------
__global__ __launch_bounds__(256) void hilo_kernel(const float* __restrict__ in,
        unsigned short* __restrict__ hi, unsigned short* __restrict__ lo,
        int n4, int has_lo) {
    int idx = blockIdx.x * 256 + threadIdx.x;
    int stride = gridDim.x * 256;
    for (int i = idx; i < n4; i += stride) {
        float4 v = reinterpret_cast<const float4*>(in)[i];
        ushort4 h;
        h.x = f2bf(v.x); h.y = f2bf(v.y); h.z = f2bf(v.z); h.w = f2bf(v.w);
        reinterpret_cast<ushort4*>(hi)[i] = h;
        if (has_lo) {
            ushort4 l;
            l.x = f2bf(v.x - bf2f(h.x));
            l.y = f2bf(v.y - bf2f(h.y));
            l.z = f2bf(v.z - bf2f(h.z));
            l.w = f2bf(v.w - bf2f(h.w));
            reinterpret_cast<ushort4*>(lo)[i] = l;
        }
    }
}

// ---------------- 128x128x32 bf16 MFMA GEMM, C = A * B^T (kept for v/proj) ----------------
#define BM 128
#define BN 128
#define BK 32
template <int TRIPLE>
__global__ __launch_bounds__(256) void gemm_bt(
    const unsigned short* __restrict__ Ahi, const unsigned short* __restrict__ Alo,
    const unsigned short* __restrict__ Bhi, const unsigned short* __restrict__ Blo,
    float* __restrict__ Cf, unsigned short* __restrict__ Cb,
    int M, int N, int K)
{
    __shared__ unsigned short lAh[BM * BK];
    __shared__ unsigned short lBh[BN * BK];
    __shared__ unsigned short lAl[BM * BK];
    __shared__ unsigned short lBl[BN * BK];

    const int tid  = threadIdx.x;
    const int wave = tid >> 6;
    const int lane = tid & 63;

    const int nTiles = N / BN;
    const int bm = blockIdx.x / nTiles;
    const int bn = blockIdx.x % nTiles;
    const int m0 = bm * BM, n0 = bn * BN;

    const int wm = (wave & 1) * 64;
    const int wn = (wave >> 1) * 64;

    f32x4 acc[4][4];
#pragma unroll
    for (int i = 0; i < 4; i++)
#pragma unroll
        for (int j = 0; j < 4; j++) acc[i][j] = (f32x4){0.f, 0.f, 0.f, 0.f};

    const int c0 = tid, c1 = tid + 256;
    const int ar0 = c0 >> 2, ac0 = (c0 & 3) * 8;
    const int ar1 = c1 >> 2, ac1 = (c1 & 3) * 8;
    const size_t off0 = (size_t)(wave * 64) * 8;
    const size_t off1 = (size_t)(256 + wave * 64) * 8;

    const int lquad = lane >> 4;
    const int l16   = lane & 15;

    const unsigned short* AhB = Ahi + (size_t)m0 * K;
    const unsigned short* BhB = Bhi + (size_t)n0 * K;
    const unsigned short* AlB = TRIPLE ? Alo + (size_t)m0 * K : nullptr;
    const unsigned short* BlB = TRIPLE ? Blo + (size_t)n0 * K : nullptr;

    for (int kk = 0; kk < K; kk += BK) {
        async_cp16(AhB + (size_t)ar0 * K + kk + ac0, &lAh[off0]);
        async_cp16(AhB + (size_t)ar1 * K + kk + ac1, &lAh[off1]);
        async_cp16(BhB + (size_t)ar0 * K + kk + ac0, &lBh[off0]);
        async_cp16(BhB + (size_t)ar1 * K + kk + ac1, &lBh[off1]);
        if (TRIPLE) {
            async_cp16(AlB + (size_t)ar0 * K + kk + ac0, &lAl[off0]);
            async_cp16(AlB + (size_t)ar1 * K + kk + ac1, &lAl[off1]);
            async_cp16(BlB + (size_t)ar0 * K + kk + ac0, &lBl[off0]);
            async_cp16(BlB + (size_t)ar1 * K + kk + ac1, &lBl[off1]);
        }
        __syncthreads();
        bf16x8 ah[4], bh[4];
#pragma unroll
        for (int i = 0; i < 4; i++)
            ah[i] = *reinterpret_cast<const bf16x8*>(&lAh[(size_t)(wm + i * 16 + l16) * BK + lquad * 8]);
#pragma unroll
        for (int j = 0; j < 4; j++)
            bh[j] = *reinterpret_cast<const bf16x8*>(&lBh[(size_t)(wn + j * 16 + l16) * BK + lquad * 8]);
#pragma unroll
        for (int i = 0; i < 4; i++)
#pragma unroll
            for (int j = 0; j < 4; j++)
                acc[i][j] = __builtin_amdgcn_mfma_f32_16x16x32_bf16(ah[i], bh[j], acc[i][j], 0, 0, 0);
        if (TRIPLE) {
            bf16x8 al[4], bl[4];
#pragma unroll
            for (int i = 0; i < 4; i++)
                al[i] = *reinterpret_cast<const bf16x8*>(&lAl[(size_t)(wm + i * 16 + l16) * BK + lquad * 8]);
#pragma unroll
            for (int j = 0; j < 4; j++)
                bl[j] = *reinterpret_cast<const bf16x8*>(&lBl[(size_t)(wn + j * 16 + l16) * BK + lquad * 8]);
#pragma unroll
            for (int i = 0; i < 4; i++)
#pragma unroll
                for (int j = 0; j < 4; j++) {
                    acc[i][j] = __builtin_amdgcn_mfma_f32_16x16x32_bf16(al[i], bh[j], acc[i][j], 0, 0, 0);
                    acc[i][j] = __builtin_amdgcn_mfma_f32_16x16x32_bf16(ah[i], bl[j], acc[i][j], 0, 0, 0);
                }
        }
        __syncthreads();
    }

    if (Cf) {
#pragma unroll
        for (int i = 0; i < 4; i++) {
            int rb = m0 + wm + i * 16 + lquad * 4;
#pragma unroll
            for (int r = 0; r < 4; r++) {
                float* crow = Cf + (size_t)(rb + r) * N + n0 + wn + l16;
#pragma unroll
                for (int j = 0; j < 4; j++) crow[j * 16] = acc[i][j][r];
            }
        }
    } else {
#pragma unroll
        for (int i = 0; i < 4; i++) {
            int rb = m0 + wm + i * 16 + lquad * 4;
#pragma unroll
            for (int r = 0; r < 4; r++) {
                unsigned short* crow = Cb + (size_t)(rb + r) * N + n0 + wn + l16;
#pragma unroll
                for (int j = 0; j < 4; j++) crow[j * 16] = f2bf(acc[i][j][r]);
            }
        }
    }
}

// ---------------- NEW: 256x256x32 triple-term pipelined GEMM (T1+T3+T4+T5) ----------------
// 8 waves (2M x 4N), 128x64 out/wave, acc[8][4]. Double-buffered LDS (128 KiB),
// 4 phases/K-tile {ds_read || 2x global_load_lds -> s_barrier -> lgkmcnt(0) -> 24 MFMA},
// one counted s_waitcnt vmcnt(2) per K-tile (never 0 mid-loop). BK=32 row stride = 64B
// -> each wave b128 frag read is a contiguous 1024B region: bank-conflict-free, no swizzle.
#define QBM 256
#define QBN 256
#define QBK 32

__global__ __launch_bounds__(512) void gemm_qk(
    const unsigned short* __restrict__ Ahi, const unsigned short* __restrict__ Alo,
    const unsigned short* __restrict__ Bhi, const unsigned short* __restrict__ Blo,
    float* __restrict__ C, int M, int N, int K)
{
    __shared__ __align__(16) unsigned short lA[2][2][QBM * QBK];   // [buf][hi/lo]
    __shared__ __align__(16) unsigned short lB[2][2][QBN * QBK];

    const int tid  = threadIdx.x;
    const int wave = tid >> 6;
    const int lane = tid & 63;
    const int l16  = lane & 15;
    const int lq   = lane >> 4;

    // XCD-aware block swizzle (gridDim.x is a multiple of 8 by launch: 2352 = 8*294)
    const int nwg = gridDim.x;
    const int cpx = nwg >> 3;
    const int bid = blockIdx.x;
    const int wg  = (bid & 7) * cpx + (bid >> 3);

    const int nTiles = N / QBN;
    const int bm = wg / nTiles, bn = wg % nTiles;
    const int m0 = bm * QBM, n0 = bn * QBN;

    const int wm = (wave >> 2) * 128;   // 2 waves along M
    const int wn = (wave & 3) * 64;     // 4 waves along N

    const unsigned short* Ah = Ahi + (size_t)m0 * K;
    const unsigned short* Al = Alo + (size_t)m0 * K;
    const unsigned short* Bh = Bhi + (size_t)n0 * K;
    const unsigned short* Bl = Blo + (size_t)n0 * K;

    // staging: 1024 16B-chunks per 256x32 array; thread t handles chunks t and t+512.
    // LDS dest is linear (chunk c -> element 8c); wave-uniform base + lane*16 by HW.
    const size_t goff0 = (size_t)(tid >> 2) * K + (size_t)(tid & 3) * 8;
    const size_t goff1 = goff0 + (size_t)128 * K;
    const int s0e = wave * 512;          // elements
    const int s1e = 4096 + wave * 512;

    const int NT = K / QBK;              // 24 for K=768 (even)

    f32x4 acc[8][4];
#pragma unroll
    for (int i = 0; i < 8; i++)
#pragma unroll
        for (int j = 0; j < 4; j++) acc[i][j] = (f32x4){0.f, 0.f, 0.f, 0.f};

#define STG(dst, gb, kk) do { \
        async_cp16((gb) + goff0 + (size_t)(kk), &(dst)[s0e]); \
        async_cp16((gb) + goff1 + (size_t)(kk), &(dst)[s1e]); } while (0)

    // raw barrier with compiler-level memory fences (no vmcnt/lgkmcnt auto-drain)
#define PBAR do { asm volatile("" ::: "memory"); \
        __builtin_amdgcn_s_barrier(); \
        asm volatile("" ::: "memory"); } while (0)

#define LGW0 do { asm volatile("s_waitcnt lgkmcnt(0)" ::: "memory"); \
        __builtin_amdgcn_sched_barrier(0); } while (0)

#define MF(H, G) do { \
    _Pragma("unroll") for (int ii = 0; ii < 4; ++ii) { \
      _Pragma("unroll") for (int jj = 0; jj < 2; ++jj) { \
        const int j = (G) * 2 + jj; \
        f32x4 a = acc[(H) * 4 + ii][j]; \
        a = __builtin_amdgcn_mfma_f32_16x16x32_bf16(ah[ii], bh[j], a, 0, 0, 0); \
        a = __builtin_amdgcn_mfma_f32_16x16x32_bf16(al[ii], bh[j], a, 0, 0, 0); \
        a = __builtin_amdgcn_mfma_f32_16x16x32_bf16(ah[ii], bl[j], a, 0, 0, 0); \
        acc[(H) * 4 + ii][j] = a; } } } while (0)

    // prologue: L(0) fully + early Bl of L(1); leave the 2 early loads in flight
    STG(lA[0][0], Ah, 0); STG(lA[0][1], Al, 0);
    STG(lB[0][0], Bh, 0); STG(lB[0][1], Bl, 0);
    STG(lB[1][1], Bl, QBK);
    asm volatile("s_waitcnt vmcnt(2)" ::: "memory");
    PBAR;

    // per K-tile T (buffer CUR): L(T+1) = {Bl @ tile T-1 ph4} + {Ah,Al,Bh @ tile T ph1-3}
#define TILE(T, CUR, NXT) do { \
    bf16x8 ah[4], al[4], bh[4], bl[4]; \
    /* phase 1: read all B + A M-half0; stage Ah(T+1) */ \
    _Pragma("unroll") for (int j = 0; j < 4; ++j) { \
        bh[j] = *reinterpret_cast<const bf16x8*>(&lB[CUR][0][(wn + j * 16 + l16) * QBK + lq * 8]); \
        bl[j] = *reinterpret_cast<const bf16x8*>(&lB[CUR][1][(wn + j * 16 + l16) * QBK + lq * 8]); } \
    _Pragma("unroll") for (int ii = 0; ii < 4; ++ii) { \
        ah[ii] = *reinterpret_cast<const bf16x8*>(&lA[CUR][0][(wm + ii * 16 + l16) * QBK + lq * 8]); \
        al[ii] = *reinterpret_cast<const bf16x8*>(&lA[CUR][1][(wm + ii * 16 + l16) * QBK + lq * 8]); } \
    if ((T) + 1 < NT) STG(lA[NXT][0], Ah, ((T) + 1) * QBK); \
    PBAR; LGW0; \
    __builtin_amdgcn_s_setprio(1); MF(0, 0); __builtin_amdgcn_s_setprio(0); \
    PBAR; \
    /* phase 2: stage Al(T+1) */ \
    if ((T) + 1 < NT) STG(lA[NXT][1], Al, ((T) + 1) * QBK); \
    PBAR; \
    __builtin_amdgcn_s_setprio(1); MF(0, 1); __builtin_amdgcn_s_setprio(0); \
    PBAR; \
    /* phase 3: read A M-half1; stage Bh(T+1) */ \
    _Pragma("unroll") for (int ii = 0; ii < 4; ++ii) { \
        ah[ii] = *reinterpret_cast<const bf16x8*>(&lA[CUR][0][(wm + 64 + ii * 16 + l16) * QBK + lq * 8]); \
        al[ii] = *reinterpret_cast<const bf16x8*>(&lA[CUR][1][(wm + 64 + ii * 16 + l16) * QBK + lq * 8]); } \
    if ((T) + 1 < NT) STG(lB[NXT][0], Bh, ((T) + 1) * QBK); \
    PBAR; LGW0; \
    __builtin_amdgcn_s_setprio(1); MF(1, 1); __builtin_amdgcn_s_setprio(0); \
    PBAR; \
    /* phase 4: stage Bl(T+2) into CUR (its bl reads finished at ph1); counted vmcnt */ \
    if ((T) + 2 < NT) STG(lB[CUR][1], Bl, ((T) + 2) * QBK); \
    PBAR; \
    __builtin_amdgcn_s_setprio(1); MF(1, 0); __builtin_amdgcn_s_setprio(0); \
    if ((T) + 1 < NT) { \
        if ((T) + 2 < NT) { asm volatile("s_waitcnt vmcnt(2)" ::: "memory"); } \
        else              { asm volatile("s_waitcnt vmcnt(0)" ::: "memory"); } \
    } \
    PBAR; \
} while (0)

    for (int t = 0; t < NT; t += 2) {
        TILE(t, 0, 1);
        TILE(t + 1, 1, 0);
    }

#undef TILE
#undef MF
#undef LGW0
#undef PBAR
#undef STG

    // epilogue: C/D layout col = lane&15, row = (lane>>4)*4 + r
#pragma unroll
    for (int i = 0; i < 8; ++i) {
        const int rb = m0 + wm + i * 16 + lq * 4;
#pragma unroll
        for (int r = 0; r < 4; ++r) {
            float* crow = C + (size_t)(rb + r) * N + n0 + wn + l16;
#pragma unroll
            for (int j = 0; j < 4; ++j) crow[j * 16] = acc[i][j][r];
        }
    }
}

// ---------------- windowed attention, one block per (window, head) ----------------
__global__ __launch_bounds__(256) void attn_kernel(
    const float* __restrict__ qk,
    const unsigned short* __restrict__ vbuf,
    unsigned short* __restrict__ attnout)
{
    const int h   = blockIdx.x % NHEAD;
    const int win = blockIdx.x / NHEAD;
    const int b   = win >> 10;
    const int wy  = (win >> 5) & 31;
    const int wx  = win & 31;

    __shared__ __align__(16) float sq[52][68];
    __shared__ __align__(16) float sk[52][68];
    __shared__ __align__(16) unsigned short sv[52][68];
    __shared__ __align__(16) float sS[52][52];
    __shared__ float rsum[WL];
    __shared__ int   rowidx[WL];

    const int tid = threadIdx.x;

    if (tid < WL) {
        int i = tid / WN, j = tid % WN;
        int ys = (wy * WN + i + 3) % IMG;
        int xs = (wx * WN + j + 3) % IMG;
        rowidx[tid] = b * (IMG * IMG) + ys * IMG + xs;
    }
    __syncthreads();

    const float LOG2_100_D16 = 0.41524101186092f;
    {
        const int hw = tid >> 5;
        const int t  = tid & 31;
        for (int pass = 0; pass < 7; ++pass) {
            int l = pass * 8 + hw;
            if (l < 49) {
                int i = l / WN, j = l % WN;
                float pos = (t < 16) ? (float)i : (float)j;
                float ang = pos * exp2f(-(float)(t & 15) * LOG2_100_D16);
                float s, c;
                __sincosf(ang, &s, &c);
                size_t base = (size_t)rowidx[l] * 1536 + h * 64;
                float q1 = qk[base + t], q2 = qk[base + t + 32];
                float k1 = qk[base + 768 + t], k2 = qk[base + 768 + t + 32];
                float nq = q1 * q1 + q2 * q2;
                float nk = k1 * k1 + k2 * k2;
#pragma unroll
                for (int m = 1; m < 32; m <<= 1) {
                    nq += __shfl_xor(nq, m);
                    nk += __shfl_xor(nk, m);
                }
                float iq = 10.f / fmaxf(sqrtf(nq), 1e-12f);
                float ik = 10.f / fmaxf(sqrtf(nk), 1e-12f);
                sq[l][t]      = (q1 * c - q2 * s) * iq;
                sq[l][t + 32] = (q1 * s + q2 * c) * iq;
                sk[l][t]      = (k1 * c - k2 * s) * ik;
                sk[l][t + 32] = (k1 * s + k2 * c) * ik;
            } else if (l < 52) {
                sq[l][t] = 0.f; sq[l][t + 32] = 0.f;
                sk[l][t] = 0.f; sk[l][t + 32] = 0.f;
            }
        }
    }
    for (int e = tid; e < 52 * 64; e += 256) {
        int l = e >> 6, d = e & 63;
        sv[l][d] = (l < 49) ? vbuf[(size_t)rowidx[l] * 768 + h * 64 + d] : (unsigned short)0;
    }
    __syncthreads();

    if (tid < 169) {
        int ta = tid / 13, tb = tid - ta * 13;
        int a0 = ta * 4, b0 = tb * 4;
        float acc[4][4];
#pragma unroll
        for (int i = 0; i < 4; i++)
#pragma unroll
            for (int j = 0; j < 4; j++) acc[i][j] = 0.f;
#pragma unroll 4
        for (int d4 = 0; d4 < 16; ++d4) {
            float4 qa[4], kb[4];
#pragma unroll
            for (int i = 0; i < 4; i++) qa[i] = *reinterpret_cast<const float4*>(&sq[a0 + i][d4 * 4]);
#pragma unroll
            for (int j = 0; j < 4; j++) kb[j] = *reinterpret_cast<const float4*>(&sk[b0 + j][d4 * 4]);
#pragma unroll
            for (int i = 0; i < 4; i++)
#pragma unroll
                for (int j = 0; j < 4; j++)
                    acc[i][j] += qa[i].x * kb[j].x + qa[i].y * kb[j].y +
                                 qa[i].z * kb[j].z + qa[i].w * kb[j].w;
        }
#pragma unroll
        for (int i = 0; i < 4; i++) {
            float4 r;
            r.x = (b0 + 0 < WL) ? acc[i][0] : -1e30f;
            r.y = (b0 + 1 < WL) ? acc[i][1] : -1e30f;
            r.z = (b0 + 2 < WL) ? acc[i][2] : -1e30f;
            r.w = (b0 + 3 < WL) ? acc[i][3] : -1e30f;
            *reinterpret_cast<float4*>(&sS[a0 + i][b0]) = r;
        }
    }
    __syncthreads();

    if (tid < WL * 4) {
        int a = tid >> 2, s4 = tid & 3;
        float m = -1e30f;
        for (int bb = s4; bb < WL; bb += 4) m = fmaxf(m, sS[a][bb]);
        m = fmaxf(m, __shfl_xor(m, 1));
        m = fmaxf(m, __shfl_xor(m, 2));
        float sum = 0.f;
        for (int bb = s4; bb < WL; bb += 4) {
            float p = __expf(sS[a][bb] - m);
            sS[a][bb] = p;
            sum += p;
        }
        sum += __shfl_xor(sum, 1);
        sum += __shfl_xor(sum, 2);
        if (s4 == 0) rsum[a] = 1.f / sum;
    }
    __syncthreads();

    if (tid < 208) {
        int ta = tid >> 4, td = tid & 15;
        int a0 = ta * 4, d0 = td * 4;
        float acc[4][4];
#pragma unroll
        for (int i = 0; i < 4; i++)
#pragma unroll
            for (int j = 0; j < 4; j++) acc[i][j] = 0.f;
        for (int bb = 0; bb < WL; ++bb) {
            float p0 = sS[a0 + 0][bb], p1 = sS[a0 + 1][bb];
            float p2 = sS[a0 + 2][bb], p3 = sS[a0 + 3][bb];
            ushort4 vr = *reinterpret_cast<const ushort4*>(&sv[bb][d0]);
            float v0 = bf2f(vr.x), v1 = bf2f(vr.y), v2 = bf2f(vr.z), v3 = bf2f(vr.w);
            acc[0][0] += p0 * v0; acc[0][1] += p0 * v1; acc[0][2] += p0 * v2; acc[0][3] += p0 * v3;
            acc[1][0] += p1 * v0; acc[1][1] += p1 * v1; acc[1][2] += p1 * v2; acc[1][3] += p1 * v3;
            acc[2][0] += p2 * v0; acc[2][1] += p2 * v1; acc[2][2] += p2 * v2; acc[2][3] += p2 * v3;
            acc[3][0] += p3 * v0; acc[3][1] += p3 * v1; acc[3][2] += p3 * v2; acc[3][3] += p3 * v3;
        }
#pragma unroll
        for (int i = 0; i < 4; i++) {
            int a = a0 + i;
            if (a < WL) {
                float r = rsum[a];
                ushort4 o;
                o.x = f2bf(acc[i][0] * r);
                o.y = f2bf(acc[i][1] * r);
                o.z = f2bf(acc[i][2] * r);
                o.w = f2bf(acc[i][3] * r);
                *reinterpret_cast<ushort4*>(&attnout[(size_t)rowidx[a] * 768 + h * 64 + d0]) = o;
            }
        }
    }
}

extern "C" void kernel_launch(void* const* d_in, const int* in_sizes, int n_in,
                              void* d_out, int out_size, void* d_ws, size_t ws_size,
                              hipStream_t stream) {
    const float* x      = (const float*)d_in[0];
    const float* qkv_w  = (const float*)d_in[1];
    const float* proj_w = (const float*)d_in[2];
    float* out = (float*)d_out;

    char* ws = (char*)d_ws;
    const size_t XE    = (size_t)NTOK * DIMC;
    const size_t WQKV  = (size_t)3 * DIMC * DIMC;
    const size_t WPROJ = (size_t)DIMC * DIMC;

    unsigned short* x_hi = (unsigned short*)ws;
    unsigned short* x_lo = x_hi + XE;
    unsigned short* w_hi = x_lo + XE;
    unsigned short* w_lo = w_hi + WQKV;
    unsigned short* p_hi = w_lo + WQKV;
    float* qkbuf = (float*)(p_hi + WPROJ);
    unsigned short* vbuf    = x_lo;   // overlay: x_lo dead after qk GEMM
    unsigned short* attnout = x_hi;   // overlay: x_hi dead after v GEMM

    size_t need = (size_t)((char*)(qkbuf + (size_t)NTOK * 1536) - ws);
    if (ws_size < need) return;

    hilo_kernel<<<8192, 256, 0, stream>>>(x, x_hi, x_lo, (int)(XE / 4), 1);
    hilo_kernel<<<1728, 256, 0, stream>>>(qkv_w, w_hi, w_lo, (int)(WQKV / 4), 1);
    hilo_kernel<<<576, 256, 0, stream>>>(proj_w, p_hi, (unsigned short*)nullptr, (int)(WPROJ / 4), 0);

    // q,k: fused 3-term split-bf16, fp32 out — NEW pipelined 256^2 kernel
    gemm_qk<<<(NTOK / 256) * (1536 / 256), 512, 0, stream>>>(
        x_hi, x_lo, w_hi, w_lo, qkbuf, NTOK, 1536, DIMC);
    // v: single, bf16 out
    gemm_bt<0><<<(NTOK / 128) * (768 / 128), 256, 0, stream>>>(
        x_hi, (unsigned short*)nullptr, w_hi + (size_t)1536 * DIMC, (unsigned short*)nullptr,
        (float*)nullptr, vbuf, NTOK, 768, DIMC);

    attn_kernel<<<2048 * NHEAD, 256, 0, stream>>>(qkbuf, vbuf, attnout);

    // proj: single, fp32 out
    gemm_bt<0><<<(NTOK / 128) * (768 / 128), 256, 0, stream>>>(
        attnout, (unsigned short*)nullptr, p_hi, (unsigned short*)nullptr,
        out, (unsigned short*)nullptr, NTOK, 768, DIMC);
}

// Round 2
// 1999.970 us; speedup vs baseline: 1.2434x; 1.1612x over previous
//
#include <hip/hip_runtime.h>
#include <cstdint>
#include <cstddef>

typedef __bf16 bf16x8 __attribute__((ext_vector_type(8)));
typedef float  f32x4  __attribute__((ext_vector_type(4)));
typedef unsigned short us8 __attribute__((ext_vector_type(8)));

typedef __attribute__((address_space(1))) void v_as1;
typedef __attribute__((address_space(3))) void v_as3;

#define NTOK 100352      // 2*224*224
#define DIMC 768
#define NHEAD 12
#define IMG 224
#define WN 7
#define WL 49

__device__ __forceinline__ unsigned short f2bf(float f) {
    uint32_t u = __float_as_uint(f);
    uint32_t r = (u + 0x7FFFu + ((u >> 16) & 1u)) >> 16;
    return (unsigned short)r;
}
__device__ __forceinline__ float bf2f(unsigned short u) {
    return __uint_as_float(((uint32_t)u) << 16);
}

__device__ __forceinline__ void async_cp16(const void* g, void* l) {
    __builtin_amdgcn_global_load_lds((v_as1*)g, (v_as3*)l, 16, 0, 0);
}

// ---------------- hi/lo bf16 split ----------------
__global__ __launch_bounds__(256) void hilo_kernel(const float* __restrict__ in,
        unsigned short* __restrict__ hi, unsigned short* __restrict__ lo,
        int n4, int has_lo) {
    int idx = blockIdx.x * 256 + threadIdx.x;
    int stride = gridDim.x * 256;
    for (int i = idx; i < n4; i += stride) {
        float4 v = reinterpret_cast<const float4*>(in)[i];
        ushort4 h;
        h.x = f2bf(v.x); h.y = f2bf(v.y); h.z = f2bf(v.z); h.w = f2bf(v.w);
        reinterpret_cast<ushort4*>(hi)[i] = h;
        if (has_lo) {
            ushort4 l;
            l.x = f2bf(v.x - bf2f(h.x));
            l.y = f2bf(v.y - bf2f(h.y));
            l.z = f2bf(v.z - bf2f(h.z));
            l.w = f2bf(v.w - bf2f(h.w));
            reinterpret_cast<ushort4*>(lo)[i] = l;
        }
    }
}

// ---------------- 128x128x32 bf16 MFMA GEMM, C = A * B^T (v/proj) ----------------
#define BM 128
#define BN 128
#define BK 32
template <int TRIPLE>
__global__ __launch_bounds__(256) void gemm_bt(
    const unsigned short* __restrict__ Ahi, const unsigned short* __restrict__ Alo,
    const unsigned short* __restrict__ Bhi, const unsigned short* __restrict__ Blo,
    float* __restrict__ Cf, unsigned short* __restrict__ Cb,
    int M, int N, int K)
{
    __shared__ unsigned short lAh[BM * BK];
    __shared__ unsigned short lBh[BN * BK];
    __shared__ unsigned short lAl[BM * BK];
    __shared__ unsigned short lBl[BN * BK];

    const int tid  = threadIdx.x;
    const int wave = tid >> 6;
    const int lane = tid & 63;

    const int nTiles = N / BN;
    const int bm = blockIdx.x / nTiles;
    const int bn = blockIdx.x % nTiles;
    const int m0 = bm * BM, n0 = bn * BN;

    const int wm = (wave & 1) * 64;
    const int wn = (wave >> 1) * 64;

    f32x4 acc[4][4];
#pragma unroll
    for (int i = 0; i < 4; i++)
#pragma unroll
        for (int j = 0; j < 4; j++) acc[i][j] = (f32x4){0.f, 0.f, 0.f, 0.f};

    const int c0 = tid, c1 = tid + 256;
    const int ar0 = c0 >> 2, ac0 = (c0 & 3) * 8;
    const int ar1 = c1 >> 2, ac1 = (c1 & 3) * 8;
    const size_t off0 = (size_t)(wave * 64) * 8;
    const size_t off1 = (size_t)(256 + wave * 64) * 8;

    const int lquad = lane >> 4;
    const int l16   = lane & 15;

    const unsigned short* AhB = Ahi + (size_t)m0 * K;
    const unsigned short* BhB = Bhi + (size_t)n0 * K;
    const unsigned short* AlB = TRIPLE ? Alo + (size_t)m0 * K : nullptr;
    const unsigned short* BlB = TRIPLE ? Blo + (size_t)n0 * K : nullptr;

    for (int kk = 0; kk < K; kk += BK) {
        async_cp16(AhB + (size_t)ar0 * K + kk + ac0, &lAh[off0]);
        async_cp16(AhB + (size_t)ar1 * K + kk + ac1, &lAh[off1]);
        async_cp16(BhB + (size_t)ar0 * K + kk + ac0, &lBh[off0]);
        async_cp16(BhB + (size_t)ar1 * K + kk + ac1, &lBh[off1]);
        if (TRIPLE) {
            async_cp16(AlB + (size_t)ar0 * K + kk + ac0, &lAl[off0]);
            async_cp16(AlB + (size_t)ar1 * K + kk + ac1, &lAl[off1]);
            async_cp16(BlB + (size_t)ar0 * K + kk + ac0, &lBl[off0]);
            async_cp16(BlB + (size_t)ar1 * K + kk + ac1, &lBl[off1]);
        }
        __syncthreads();
        bf16x8 ah[4], bh[4];
#pragma unroll
        for (int i = 0; i < 4; i++)
            ah[i] = *reinterpret_cast<const bf16x8*>(&lAh[(size_t)(wm + i * 16 + l16) * BK + lquad * 8]);
#pragma unroll
        for (int j = 0; j < 4; j++)
            bh[j] = *reinterpret_cast<const bf16x8*>(&lBh[(size_t)(wn + j * 16 + l16) * BK + lquad * 8]);
#pragma unroll
        for (int i = 0; i < 4; i++)
#pragma unroll
            for (int j = 0; j < 4; j++)
                acc[i][j] = __builtin_amdgcn_mfma_f32_16x16x32_bf16(ah[i], bh[j], acc[i][j], 0, 0, 0);
        if (TRIPLE) {
            bf16x8 al[4], bl[4];
#pragma unroll
            for (int i = 0; i < 4; i++)
                al[i] = *reinterpret_cast<const bf16x8*>(&lAl[(size_t)(wm + i * 16 + l16) * BK + lquad * 8]);
#pragma unroll
            for (int j = 0; j < 4; j++)
                bl[j] = *reinterpret_cast<const bf16x8*>(&lBl[(size_t)(wn + j * 16 + l16) * BK + lquad * 8]);
#pragma unroll
            for (int i = 0; i < 4; i++)
#pragma unroll
                for (int j = 0; j < 4; j++) {
                    acc[i][j] = __builtin_amdgcn_mfma_f32_16x16x32_bf16(al[i], bh[j], acc[i][j], 0, 0, 0);
                    acc[i][j] = __builtin_amdgcn_mfma_f32_16x16x32_bf16(ah[i], bl[j], acc[i][j], 0, 0, 0);
                }
        }
        __syncthreads();
    }

    if (Cf) {
#pragma unroll
        for (int i = 0; i < 4; i++) {
            int rb = m0 + wm + i * 16 + lquad * 4;
#pragma unroll
            for (int r = 0; r < 4; r++) {
                float* crow = Cf + (size_t)(rb + r) * N + n0 + wn + l16;
#pragma unroll
                for (int j = 0; j < 4; j++) crow[j * 16] = acc[i][j][r];
            }
        }
    } else {
#pragma unroll
        for (int i = 0; i < 4; i++) {
            int rb = m0 + wm + i * 16 + lquad * 4;
#pragma unroll
            for (int r = 0; r < 4; r++) {
                unsigned short* crow = Cb + (size_t)(rb + r) * N + n0 + wn + l16;
#pragma unroll
                for (int j = 0; j < 4; j++) crow[j * 16] = f2bf(acc[i][j][r]);
            }
        }
    }
}

// ---------------- 256x256x32 triple-term pipelined GEMM (qk) — unchanged ----------------
#define QBM 256
#define QBN 256
#define QBK 32

__global__ __launch_bounds__(512) void gemm_qk(
    const unsigned short* __restrict__ Ahi, const unsigned short* __restrict__ Alo,
    const unsigned short* __restrict__ Bhi, const unsigned short* __restrict__ Blo,
    float* __restrict__ C, int M, int N, int K)
{
    __shared__ __align__(16) unsigned short lA[2][2][QBM * QBK];   // [buf][hi/lo]
    __shared__ __align__(16) unsigned short lB[2][2][QBN * QBK];

    const int tid  = threadIdx.x;
    const int wave = tid >> 6;
    const int lane = tid & 63;
    const int l16  = lane & 15;
    const int lq   = lane >> 4;

    const int nwg = gridDim.x;
    const int cpx = nwg >> 3;
    const int bid = blockIdx.x;
    const int wg  = (bid & 7) * cpx + (bid >> 3);

    const int nTiles = N / QBN;
    const int bm = wg / nTiles, bn = wg % nTiles;
    const int m0 = bm * QBM, n0 = bn * QBN;

    const int wm = (wave >> 2) * 128;
    const int wn = (wave & 3) * 64;

    const unsigned short* Ah = Ahi + (size_t)m0 * K;
    const unsigned short* Al = Alo + (size_t)m0 * K;
    const unsigned short* Bh = Bhi + (size_t)n0 * K;
    const unsigned short* Bl = Blo + (size_t)n0 * K;

    const size_t goff0 = (size_t)(tid >> 2) * K + (size_t)(tid & 3) * 8;
    const size_t goff1 = goff0 + (size_t)128 * K;
    const int s0e = wave * 512;
    const int s1e = 4096 + wave * 512;

    const int NT = K / QBK;

    f32x4 acc[8][4];
#pragma unroll
    for (int i = 0; i < 8; i++)
#pragma unroll
        for (int j = 0; j < 4; j++) acc[i][j] = (f32x4){0.f, 0.f, 0.f, 0.f};

#define STG(dst, gb, kk) do { \
        async_cp16((gb) + goff0 + (size_t)(kk), &(dst)[s0e]); \
        async_cp16((gb) + goff1 + (size_t)(kk), &(dst)[s1e]); } while (0)

#define PBAR do { asm volatile("" ::: "memory"); \
        __builtin_amdgcn_s_barrier(); \
        asm volatile("" ::: "memory"); } while (0)

#define LGW0 do { asm volatile("s_waitcnt lgkmcnt(0)" ::: "memory"); \
        __builtin_amdgcn_sched_barrier(0); } while (0)

#define MF(H, G) do { \
    _Pragma("unroll") for (int ii = 0; ii < 4; ++ii) { \
      _Pragma("unroll") for (int jj = 0; jj < 2; ++jj) { \
        const int j = (G) * 2 + jj; \
        f32x4 a = acc[(H) * 4 + ii][j]; \
        a = __builtin_amdgcn_mfma_f32_16x16x32_bf16(ah[ii], bh[j], a, 0, 0, 0); \
        a = __builtin_amdgcn_mfma_f32_16x16x32_bf16(al[ii], bh[j], a, 0, 0, 0); \
        a = __builtin_amdgcn_mfma_f32_16x16x32_bf16(ah[ii], bl[j], a, 0, 0, 0); \
        acc[(H) * 4 + ii][j] = a; } } } while (0)

    STG(lA[0][0], Ah, 0); STG(lA[0][1], Al, 0);
    STG(lB[0][0], Bh, 0); STG(lB[0][1], Bl, 0);
    STG(lB[1][1], Bl, QBK);
    asm volatile("s_waitcnt vmcnt(2)" ::: "memory");
    PBAR;

#define TILE(T, CUR, NXT) do { \
    bf16x8 ah[4], al[4], bh[4], bl[4]; \
    _Pragma("unroll") for (int j = 0; j < 4; ++j) { \
        bh[j] = *reinterpret_cast<const bf16x8*>(&lB[CUR][0][(wn + j * 16 + l16) * QBK + lq * 8]); \
        bl[j] = *reinterpret_cast<const bf16x8*>(&lB[CUR][1][(wn + j * 16 + l16) * QBK + lq * 8]); } \
    _Pragma("unroll") for (int ii = 0; ii < 4; ++ii) { \
        ah[ii] = *reinterpret_cast<const bf16x8*>(&lA[CUR][0][(wm + ii * 16 + l16) * QBK + lq * 8]); \
        al[ii] = *reinterpret_cast<const bf16x8*>(&lA[CUR][1][(wm + ii * 16 + l16) * QBK + lq * 8]); } \
    if ((T) + 1 < NT) STG(lA[NXT][0], Ah, ((T) + 1) * QBK); \
    PBAR; LGW0; \
    __builtin_amdgcn_s_setprio(1); MF(0, 0); __builtin_amdgcn_s_setprio(0); \
    PBAR; \
    if ((T) + 1 < NT) STG(lA[NXT][1], Al, ((T) + 1) * QBK); \
    PBAR; \
    __builtin_amdgcn_s_setprio(1); MF(0, 1); __builtin_amdgcn_s_setprio(0); \
    PBAR; \
    _Pragma("unroll") for (int ii = 0; ii < 4; ++ii) { \
        ah[ii] = *reinterpret_cast<const bf16x8*>(&lA[CUR][0][(wm + 64 + ii * 16 + l16) * QBK + lq * 8]); \
        al[ii] = *reinterpret_cast<const bf16x8*>(&lA[CUR][1][(wm + 64 + ii * 16 + l16) * QBK + lq * 8]); } \
    if ((T) + 1 < NT) STG(lB[NXT][0], Bh, ((T) + 1) * QBK); \
    PBAR; LGW0; \
    __builtin_amdgcn_s_setprio(1); MF(1, 1); __builtin_amdgcn_s_setprio(0); \
    PBAR; \
    if ((T) + 2 < NT) STG(lB[CUR][1], Bl, ((T) + 2) * QBK); \
    PBAR; \
    __builtin_amdgcn_s_setprio(1); MF(1, 0); __builtin_amdgcn_s_setprio(0); \
    if ((T) + 1 < NT) { \
        if ((T) + 2 < NT) { asm volatile("s_waitcnt vmcnt(2)" ::: "memory"); } \
        else              { asm volatile("s_waitcnt vmcnt(0)" ::: "memory"); } \
    } \
    PBAR; \
} while (0)

    for (int t = 0; t < NT; t += 2) {
        TILE(t, 0, 1);
        TILE(t + 1, 1, 0);
    }

#undef TILE
#undef MF
#undef LGW0
#undef PBAR
#undef STG

#pragma unroll
    for (int i = 0; i < 8; ++i) {
        const int rb = m0 + wm + i * 16 + lq * 4;
#pragma unroll
        for (int r = 0; r < 4; ++r) {
            float* crow = C + (size_t)(rb + r) * N + n0 + wn + l16;
#pragma unroll
            for (int j = 0; j < 4; ++j) crow[j * 16] = acc[i][j][r];
        }
    }
}

// ---------------- NEW: MFMA windowed attention, one block per (window, head) ----------------
// 4 waves; wave w owns output rows [16w,16w+16). L padded 49->64.
// q,k staged as split bf16 hi/lo (triple-product QK^T preserves fp32-level logits).
// P split hi/lo for PV. XOR-swizzled LDS (row&7 based) kills the 128B-stride b128 conflicts.
// Overlays: Ph=qh, Pl=ql, Vt=kh (dead after QK^T). V loaded to regs early (T14).
__global__ __launch_bounds__(256) void attn_kernel(
    const float* __restrict__ qk,
    const unsigned short* __restrict__ vbuf,
    unsigned short* __restrict__ attnout)
{
    const int h   = blockIdx.x % NHEAD;
    const int win = blockIdx.x / NHEAD;
    const int b   = win >> 10;
    const int wy  = (win >> 5) & 31;
    const int wx  = win & 31;

    __shared__ __align__(16) unsigned short qh[64 * 64];   // later Ph
    __shared__ __align__(16) unsigned short ql[64 * 64];   // later Pl
    __shared__ __align__(16) unsigned short kh[64 * 64];   // later Vt (transposed V)
    __shared__ __align__(16) unsigned short kl[64 * 64];
    __shared__ __align__(16) float sS[64 * 64];            // logits -> exp, swizzled
    __shared__ float rsum[WL];
    __shared__ int   rowidx[WL];

    unsigned short* Ph = qh;
    unsigned short* Pl = ql;
    unsigned short* Vt = kh;

    const int tid  = threadIdx.x;
    const int wave = tid >> 6;
    const int lane = tid & 63;
    const int l16  = lane & 15;
    const int lq   = lane >> 4;
    const int wm16 = wave * 16;

    if (tid < WL) {
        int i = tid / WN, j = tid % WN;
        int ys = (wy * WN + i + 3) % IMG;
        int xs = (wx * WN + j + 3) % IMG;
        rowidx[tid] = b * (IMG * IMG) + ys * IMG + xs;
    }
    __syncthreads();

    // ---- V -> regs early (32B/thread, coalesced); written to LDS transposed later
    const int vl = tid >> 2, vd0 = (tid & 3) * 16;
    us8 vr0 = (us8)0, vr1 = (us8)0;
    if (tid < 196) {
        const us8* vp = reinterpret_cast<const us8*>(vbuf + (size_t)rowidx[vl] * 768 + h * 64 + vd0);
        vr0 = vp[0]; vr1 = vp[1];
    }

    // ---- stage q,k: RoPE + fused 10/||.||, split to bf16 hi/lo, swizzled writes
    const float LOG2_100_D16 = 0.41524101186092f;  // log2(100)/16
    {
        const int hw = tid >> 5;   // 0..7
        const int t  = tid & 31;   // pair (t, t+32)
        for (int pass = 0; pass < 8; ++pass) {
            int l = pass * 8 + hw;
            if (l < WL) {
                int i = l / WN, j = l % WN;
                float pos = (t < 16) ? (float)i : (float)j;
                float ang = pos * exp2f(-(float)(t & 15) * LOG2_100_D16);
                float s, c;
                __sincosf(ang, &s, &c);
                size_t base = (size_t)rowidx[l] * 1536 + h * 64;
                float q1 = qk[base + t], q2 = qk[base + t + 32];
                float k1 = qk[base + 768 + t], k2 = qk[base + 768 + t + 32];
                float nq = q1 * q1 + q2 * q2;
                float nk = k1 * k1 + k2 * k2;
#pragma unroll
                for (int m = 1; m < 32; m <<= 1) {
                    nq += __shfl_xor(nq, m);
                    nk += __shfl_xor(nk, m);
                }
                float iq = 10.f / fmaxf(sqrtf(nq), 1e-12f);
                float ik = 10.f / fmaxf(sqrtf(nk), 1e-12f);
                float qv1 = (q1 * c - q2 * s) * iq;
                float qv2 = (q1 * s + q2 * c) * iq;
                float kv1 = (k1 * c - k2 * s) * ik;
                float kv2 = (k1 * s + k2 * c) * ik;
                const int rb = l << 6, sw = (l & 7) << 3;
                int e1 = rb + (t ^ sw);
                int e2 = rb + ((t + 32) ^ sw);
                unsigned short hv;
                hv = f2bf(qv1); qh[e1] = hv; ql[e1] = f2bf(qv1 - bf2f(hv));
                hv = f2bf(qv2); qh[e2] = hv; ql[e2] = f2bf(qv2 - bf2f(hv));
                hv = f2bf(kv1); kh[e1] = hv; kl[e1] = f2bf(kv1 - bf2f(hv));
                hv = f2bf(kv2); kh[e2] = hv; kl[e2] = f2bf(kv2 - bf2f(hv));
            } else if (l < 64) {
                const int rb = l << 6, sw = (l & 7) << 3;
                int e1 = rb + (t ^ sw);
                int e2 = rb + ((t + 32) ^ sw);
                qh[e1] = 0; ql[e1] = 0; qh[e2] = 0; ql[e2] = 0;
                kh[e1] = 0; kl[e1] = 0; kh[e2] = 0; kl[e2] = 0;
            }
        }
    }
    __syncthreads();

    // ---- QK^T: wave w computes S rows [16w,16w+16) x 64, triple bf16 product
    {
        f32x4 accq[4];
#pragma unroll
        for (int j = 0; j < 4; j++) accq[j] = (f32x4){0.f, 0.f, 0.f, 0.f};

        bf16x8 ah[2], al[2];
        const int arow = wm16 + l16;
        const int asw = (arow & 7) << 3;
#pragma unroll
        for (int s = 0; s < 2; ++s) {
            int e = (arow << 6) + ((s * 32 + lq * 8) ^ asw);
            ah[s] = *reinterpret_cast<const bf16x8*>(&qh[e]);
            al[s] = *reinterpret_cast<const bf16x8*>(&ql[e]);
        }
#pragma unroll
        for (int j = 0; j < 4; ++j) {
            const int brow = j * 16 + l16;
            const int bsw = (brow & 7) << 3;
#pragma unroll
            for (int s = 0; s < 2; ++s) {
                int e = (brow << 6) + ((s * 32 + lq * 8) ^ bsw);
                bf16x8 bh = *reinterpret_cast<const bf16x8*>(&kh[e]);
                bf16x8 bl = *reinterpret_cast<const bf16x8*>(&kl[e]);
                accq[j] = __builtin_amdgcn_mfma_f32_16x16x32_bf16(ah[s], bh, accq[j], 0, 0, 0);
                accq[j] = __builtin_amdgcn_mfma_f32_16x16x32_bf16(al[s], bh, accq[j], 0, 0, 0);
                accq[j] = __builtin_amdgcn_mfma_f32_16x16x32_bf16(ah[s], bl, accq[j], 0, 0, 0);
            }
        }
        // write S (fp32, swizzled by (row&7)<<2)
#pragma unroll
        for (int j = 0; j < 4; ++j) {
#pragma unroll
            for (int r = 0; r < 4; ++r) {
                int row = wm16 + lq * 4 + r;
                int e = (row << 6) + ((j * 16 + l16) ^ ((row & 7) << 2));
                sS[e] = accq[j][r];
            }
        }
    }
    __syncthreads();

    // ---- softmax: 4 lanes per row (rows < 49 only; padded S regions are exact 0)
    if (tid < WL * 4) {
        int a = tid >> 2, s4 = tid & 3;
        const int rb = a << 6, sw = (a & 7) << 2;
        float m = -1e30f;
        for (int bb = s4; bb < WL; bb += 4) m = fmaxf(m, sS[rb + (bb ^ sw)]);
        m = fmaxf(m, __shfl_xor(m, 1));
        m = fmaxf(m, __shfl_xor(m, 2));
        float sum = 0.f;
        for (int bb = s4; bb < WL; bb += 4) {
            int e = rb + (bb ^ sw);
            float p = __expf(sS[e] - m);
            sS[e] = p;
            sum += p;
        }
        sum += __shfl_xor(sum, 1);
        sum += __shfl_xor(sum, 2);
        if (s4 == 0) rsum[a] = 1.f / sum;
    }
    __syncthreads();

    // ---- P -> bf16 hi/lo (overlay qh/ql) + Vt scatter-write (overlay kh)
    {
        const int q = tid >> 2, l0 = (tid & 3) << 4;
        const int sw32 = (q & 7) << 2, sw16 = (q & 7) << 3;
#pragma unroll
        for (int g = 0; g < 4; ++g) {
            int l = l0 + g * 4;
            float4 pv = *reinterpret_cast<const float4*>(&sS[(q << 6) + (l ^ sw32)]);
            ushort4 hb, lb;
            hb.x = f2bf(pv.x); lb.x = f2bf(pv.x - bf2f(hb.x));
            hb.y = f2bf(pv.y); lb.y = f2bf(pv.y - bf2f(hb.y));
            hb.z = f2bf(pv.z); lb.z = f2bf(pv.z - bf2f(hb.z));
            hb.w = f2bf(pv.w); lb.w = f2bf(pv.w - bf2f(hb.w));
            int e = (q << 6) + (l ^ sw16);
            *reinterpret_cast<ushort4*>(&Ph[e]) = hb;
            *reinterpret_cast<ushort4*>(&Pl[e]) = lb;
        }
    }
    if (tid < 196) {
#pragma unroll
        for (int i = 0; i < 8; ++i) {
            int d = vd0 + i;
            Vt[(d << 6) + (vl ^ ((d & 7) << 3))] = vr0[i];
        }
#pragma unroll
        for (int i = 0; i < 8; ++i) {
            int d = vd0 + 8 + i;
            Vt[(d << 6) + (vl ^ ((d & 7) << 3))] = vr1[i];
        }
    }
    // note: Vt cols l>=49 hold stale kh data, but P[:, l>=49] == 0 exactly, so PV is safe.
    __syncthreads();

    // ---- PV: O rows [16w,16w+16) = (Ph + Pl) * V
    {
        f32x4 acco[4];
#pragma unroll
        for (int j = 0; j < 4; j++) acco[j] = (f32x4){0.f, 0.f, 0.f, 0.f};

        bf16x8 ph[2], pl[2];
        const int arow = wm16 + l16;
        const int asw = (arow & 7) << 3;
#pragma unroll
        for (int s = 0; s < 2; ++s) {
            int e = (arow << 6) + ((s * 32 + lq * 8) ^ asw);
            ph[s] = *reinterpret_cast<const bf16x8*>(&Ph[e]);
            pl[s] = *reinterpret_cast<const bf16x8*>(&Pl[e]);
        }
#pragma unroll
        for (int j = 0; j < 4; ++j) {
            const int drow = j * 16 + l16;
            const int dsw = (drow & 7) << 3;
#pragma unroll
            for (int s = 0; s < 2; ++s) {
                int e = (drow << 6) + ((s * 32 + lq * 8) ^ dsw);
                bf16x8 vv = *reinterpret_cast<const bf16x8*>(&Vt[e]);
                acco[j] = __builtin_amdgcn_mfma_f32_16x16x32_bf16(ph[s], vv, acco[j], 0, 0, 0);
                acco[j] = __builtin_amdgcn_mfma_f32_16x16x32_bf16(pl[s], vv, acco[j], 0, 0, 0);
            }
        }
        // output: col = l16 (+j*16), row = lq*4 + r
#pragma unroll
        for (int r = 0; r < 4; ++r) {
            int q = wm16 + lq * 4 + r;
            if (q < WL) {
                float rv = rsum[q];
                size_t gbase = (size_t)rowidx[q] * 768 + h * 64;
#pragma unroll
                for (int j = 0; j < 4; ++j)
                    attnout[gbase + j * 16 + l16] = f2bf(acco[j][r] * rv);
            }
        }
    }
}

extern "C" void kernel_launch(void* const* d_in, const int* in_sizes, int n_in,
                              void* d_out, int out_size, void* d_ws, size_t ws_size,
                              hipStream_t stream) {
    const float* x      = (const float*)d_in[0];
    const float* qkv_w  = (const float*)d_in[1];
    const float* proj_w = (const float*)d_in[2];
    float* out = (float*)d_out;

    char* ws = (char*)d_ws;
    const size_t XE    = (size_t)NTOK * DIMC;
    const size_t WQKV  = (size_t)3 * DIMC * DIMC;
    const size_t WPROJ = (size_t)DIMC * DIMC;

    unsigned short* x_hi = (unsigned short*)ws;
    unsigned short* x_lo = x_hi + XE;
    unsigned short* w_hi = x_lo + XE;
    unsigned short* w_lo = w_hi + WQKV;
    unsigned short* p_hi = w_lo + WQKV;
    float* qkbuf = (float*)(p_hi + WPROJ);
    unsigned short* vbuf    = x_lo;   // overlay: x_lo dead after qk GEMM
    unsigned short* attnout = x_hi;   // overlay: x_hi dead after v GEMM

    size_t need = (size_t)((char*)(qkbuf + (size_t)NTOK * 1536) - ws);
    if (ws_size < need) return;

    hilo_kernel<<<8192, 256, 0, stream>>>(x, x_hi, x_lo, (int)(XE / 4), 1);
    hilo_kernel<<<1728, 256, 0, stream>>>(qkv_w, w_hi, w_lo, (int)(WQKV / 4), 1);
    hilo_kernel<<<576, 256, 0, stream>>>(proj_w, p_hi, (unsigned short*)nullptr, (int)(WPROJ / 4), 0);

    // q,k: fused 3-term split-bf16, fp32 out — pipelined 256^2 kernel
    gemm_qk<<<(NTOK / 256) * (1536 / 256), 512, 0, stream>>>(
        x_hi, x_lo, w_hi, w_lo, qkbuf, NTOK, 1536, DIMC);
    // v: single, bf16 out
    gemm_bt<0><<<(NTOK / 128) * (768 / 128), 256, 0, stream>>>(
        x_hi, (unsigned short*)nullptr, w_hi + (size_t)1536 * DIMC, (unsigned short*)nullptr,
        (float*)nullptr, vbuf, NTOK, 768, DIMC);

    attn_kernel<<<2048 * NHEAD, 256, 0, stream>>>(qkbuf, vbuf, attnout);

    // proj: single, fp32 out
    gemm_bt<0><<<(NTOK / 128) * (768 / 128), 256, 0, stream>>>(
        attnout, (unsigned short*)nullptr, p_hi, (unsigned short*)nullptr,
        out, (unsigned short*)nullptr, NTOK, 768, DIMC);
}